// Round 4
// baseline (354.678 us; speedup 1.0000x reference)
//
#include <hip/hip_runtime.h>

typedef unsigned short u16;
typedef __attribute__((ext_vector_type(8))) short bf16x8;
typedef __attribute__((ext_vector_type(4))) float f32x4;

#define HID 2048
#define NH 16
#define QLR 1536
#define KVLR 512
#define DR 64
#define DN 128
#define DQK 192
#define DV 128
#define SEQ 2048
#define NKVA 2176
#define SCALE 0.07216878364870323f  // 192^-0.5
#define NTASK 5120
#define NMERGE 1536

static __device__ __forceinline__ u16 f2bf(float f) {
  unsigned v = __builtin_bit_cast(unsigned, f);
  v = v + 0x7fffu + ((v >> 16) & 1u);
  return (u16)(v >> 16);
}
static __device__ __forceinline__ float bf2f(u16 u) {
  unsigned v = ((unsigned)u) << 16;
  return __builtin_bit_cast(float, v);
}

#define GLOAD16(gp, lp)                                                        \
  __builtin_amdgcn_global_load_lds(                                            \
      (const __attribute__((address_space(1))) void*)(gp),                     \
      (__attribute__((address_space(3))) void*)(lp), 16, 0, 0)

// ---------------- f32 -> bf16 convert; trailing region (i >= nsrc) zeroed ----
__global__ void k_convert(const float* __restrict__ src, u16* __restrict__ dst,
                          long nsrc, long ndst) {
  long i = ((long)blockIdx.x * blockDim.x + threadIdx.x) * 4;
  long stride = (long)gridDim.x * blockDim.x * 4;
  for (; i < ndst; i += stride) {
    u16 o0 = 0, o1 = 0, o2 = 0, o3 = 0;
    if (i < nsrc) {
      const float4 f = *(const float4*)(src + i);
      o0 = f2bf(f.x); o1 = f2bf(f.y); o2 = f2bf(f.z); o3 = f2bf(f.w);
    }
    u16* d = dst + i;
    d[0] = o0; d[1] = o1; d[2] = o2; d[3] = o3;
  }
}

// ---------------- row RMSNorm ----------------
__global__ void k_rmsnorm(const float* __restrict__ X, const float* __restrict__ w,
                          u16* __restrict__ Y, int xstride, int cols, float inv_cols) {
  const int row = blockIdx.x;
  const int t = threadIdx.x;
  const float* x = X + (size_t)row * xstride;
  float ss = 0.f;
  for (int i = t * 4; i < cols; i += 1024) {
    float4 v = *(const float4*)(x + i);
    ss += v.x * v.x + v.y * v.y + v.z * v.z + v.w * v.w;
  }
#pragma unroll
  for (int m = 1; m < 64; m <<= 1) ss += __shfl_xor(ss, m, 64);
  __shared__ float red[4];
  if ((t & 63) == 0) red[t >> 6] = ss;
  __syncthreads();
  float tot = red[0] + red[1] + red[2] + red[3];
  float r = rsqrtf(tot * inv_cols + 1e-6f);
  for (int i = t * 4; i < cols; i += 1024) {
    float4 v = *(const float4*)(x + i);
    float4 g = *(const float4*)(w + i);
    u16* y = Y + (size_t)row * cols + i;
    y[0] = f2bf(v.x * r * g.x);
    y[1] = f2bf(v.y * r * g.y);
    y[2] = f2bf(v.z * r * g.z);
    y[3] = f2bf(v.w * r * g.w);
  }
}

// ---------------- NT GEMM (m97-style 128x128, XCD swizzle) ----------------
__global__ __launch_bounds__(256) void k_gemm_nt(
    const u16* __restrict__ A, const u16* __restrict__ B, void* __restrict__ Cout,
    int M, int N, int K, int c_bf16) {
  __shared__ __align__(16) u16 As[4096];
  __shared__ __align__(16) u16 Bs[4096];
  const int t = threadIdx.x;
  const int lane = t & 63;
  const int w = t >> 6, wr = w >> 1, wc = w & 1;
  const int lm = lane & 15, lg = lane >> 4;

  const int nwg = gridDim.x * gridDim.y;
  int bid = blockIdx.y * gridDim.x + blockIdx.x;
  if ((nwg & 7) == 0) bid = (bid & 7) * (nwg >> 3) + (bid >> 3);
  const int bm = bid % gridDim.y;
  const int bn = bid / gridDim.y;

  const u16* a0 = A + (size_t)(bm * 128 + (t >> 2)) * K + (t & 3) * 8;
  const u16* b0 = B + (size_t)(bn * 128 + (t >> 2)) * K + (t & 3) * 8;
  const size_t rK = (size_t)64 * K;
  u16* as0 = As + t * 8;
  u16* bs0 = Bs + t * 8;

  f32x4 acc[4][4] = {};
  for (int kt = 0; kt < K; kt += 32) {
    GLOAD16(a0 + kt, as0);
    GLOAD16(a0 + rK + kt, as0 + 2048);
    GLOAD16(b0 + kt, bs0);
    GLOAD16(b0 + rK + kt, bs0 + 2048);
    __syncthreads();
    bf16x8 af[4], bfr[4];
#pragma unroll
    for (int i = 0; i < 4; ++i)
      af[i] = *(const bf16x8*)(As + (wr * 64 + i * 16 + lm) * 32 + lg * 8);
#pragma unroll
    for (int j = 0; j < 4; ++j)
      bfr[j] = *(const bf16x8*)(Bs + (wc * 64 + j * 16 + lm) * 32 + lg * 8);
#pragma unroll
    for (int i = 0; i < 4; ++i)
#pragma unroll
      for (int j = 0; j < 4; ++j)
        acc[i][j] = __builtin_amdgcn_mfma_f32_16x16x32_bf16(af[i], bfr[j], acc[i][j], 0, 0, 0);
    __syncthreads();
  }
  const int row0 = bm * 128 + wr * 64 + lg * 4;
  const int col0 = bn * 128 + wc * 64 + lm;
  if (c_bf16) {
    u16* C = (u16*)Cout;
#pragma unroll
    for (int i = 0; i < 4; ++i)
#pragma unroll
      for (int r = 0; r < 4; ++r) {
        u16* crow = C + (size_t)(row0 + i * 16 + r) * N + col0;
#pragma unroll
        for (int j = 0; j < 4; ++j) crow[j * 16] = f2bf(acc[i][j][r]);
      }
  } else {
    float* C = (float*)Cout;
#pragma unroll
    for (int i = 0; i < 4; ++i)
#pragma unroll
      for (int r = 0; r < 4; ++r) {
        float* crow = C + (size_t)(row0 + i * 16 + r) * N + col0;
#pragma unroll
        for (int j = 0; j < 4; ++j) crow[j * 16] = acc[i][j][r];
      }
  }
}

// ------- assemble qf (pre-scaled) ----------
__global__ void k_mk_qf(const u16* __restrict__ qfull, const float* __restrict__ cosb,
                        const float* __restrict__ sinb, u16* __restrict__ qf) {
  const int s = blockIdx.x, h = blockIdx.y, t = threadIdx.x;
  const u16* src = qfull + (size_t)s * (NH * DQK) + h * DQK;
  u16* dst = qf + ((size_t)h * SEQ + s) * DQK;
  dst[t] = f2bf(bf2f(src[t]) * SCALE);
  if (t < 32) {
    float a = bf2f(src[DN + 2 * t]);
    float b = bf2f(src[DN + 2 * t + 1]);
    float c = cosb[(size_t)s * DR + t];
    float sn = sinb[(size_t)s * DR + t];
    dst[DN + t] = f2bf((a * c - b * sn) * SCALE);
    dst[DN + 32 + t] = f2bf((b * c + a * sn) * SCALE);
  }
}

// -------- assemble kf and v_t[h][d][s] --------
__global__ void k_mk_kf_v(const u16* __restrict__ kvfull, const float* __restrict__ krot,
                          int krot_stride, const float* __restrict__ cosb,
                          const float* __restrict__ sinb, u16* __restrict__ kf,
                          u16* __restrict__ vt) {
  const int s = blockIdx.x, h = blockIdx.y, t = threadIdx.x;
  const u16* src = kvfull + (size_t)s * (NH * 256) + h * 256;
  u16* kdst = kf + ((size_t)h * SEQ + s) * DQK;
  kdst[t] = src[t];
  vt[((size_t)h * DV + t) * SEQ + s] = src[DN + t];
  if (t < 32) {
    float a = krot[(size_t)s * krot_stride + 2 * t];
    float b = krot[(size_t)s * krot_stride + 2 * t + 1];
    float c = cosb[(size_t)s * DR + t];
    float sn = sinb[(size_t)s * DR + t];
    kdst[DN + t] = f2bf(a * c - b * sn);
    kdst[DN + 32 + t] = f2bf(b * c + a * sn);
  }
}

// ---------------- flash attention v4: split-K tasks (flash-decoding) ---------
// 5120 1-wave tasks = (head, q16-tile, 256-kv chunk); <=8 iters each.
// Hardcodes cu = [0,1024,2048] (fixed by setup_inputs). Partials (m,l,O) in
// f32 workspace; k_merge combines. Single-chunk tiles write final directly.
__global__ __launch_bounds__(64) void k_attn(
    const u16* __restrict__ qf, const u16* __restrict__ kf, const u16* __restrict__ vt,
    u16* __restrict__ attn_out, float* __restrict__ O_part, float* __restrict__ mlbuf) {
  const int bid = blockIdx.x;
  const int lane = threadIdx.x & 63;
  const int lm = lane & 15, lg = lane >> 4;
  const int x = bid & 7, t7 = bid >> 3;   // t7 in [0,640)
  const int hh = t7 & 1, u = t7 >> 1;     // u in [0,320)
  const int h = x * 2 + hh;               // 2 heads per XCD
  const int seg = u >= 160;
  const int v = u - seg * 160;
  int j, c, nc;
  if (v < 64)       { j = 48 + (v >> 2); c = v & 3; nc = 4; }
  else if (v < 112) { int w2 = v - 64;  j = 32 + w2 / 3;   c = w2 % 3; nc = 3; }
  else if (v < 144) { int w2 = v - 112; j = 16 + (w2 >> 1); c = w2 & 1; nc = 2; }
  else              { j = v - 144; c = 0; nc = 1; }
  const int qi = seg * 64 + j;
  const int lo_row = qi * 16;
  const int n_it = (j >> 1) + 1;
  int kt = seg * 32 + c * 8;
  const int ktN = seg * 32 + (n_it < (c + 1) * 8 ? n_it : (c + 1) * 8);

  bf16x8 qfr[6];
  {
    const u16* qp = qf + ((size_t)h * SEQ + (lo_row + lm)) * DQK + lg * 8;
#pragma unroll
    for (int cc = 0; cc < 6; ++cc) qfr[cc] = *(const bf16x8*)(qp + cc * 32);
  }
  int qrow[4];
#pragma unroll
  for (int r = 0; r < 4; ++r) qrow[r] = lo_row + lg * 4 + r;

  float m_r[4], l_loc[4];
#pragma unroll
  for (int r = 0; r < 4; ++r) { m_r[r] = -3.0e4f; l_loc[r] = 0.f; }
  f32x4 oacc[8] = {};

  __shared__ __align__(16) u16 p_lds[16][32];
  bf16x8 kA[12], kB[12], vv[8];

#define LOADK(kreg, kt_)                                                       \
  do {                                                                         \
    const u16* kp_ = kf + ((size_t)h * SEQ + (kt_) * 32 + lm) * DQK + lg * 8;  \
    _Pragma("unroll") for (int n0_ = 0; n0_ < 2; ++n0_)                        \
        _Pragma("unroll") for (int c_ = 0; c_ < 6; ++c_)                       \
            kreg[n0_ * 6 + c_] =                                               \
        *(const bf16x8*)(kp_ + (size_t)n0_ * 16 * DQK + c_ * 32);              \
  } while (0)

#define LOADV(kt_)                                                             \
  do {                                                                         \
    const u16* vp_ = vt + ((size_t)h * DV + lm) * SEQ + (kt_) * 32 + lg * 8;   \
    _Pragma("unroll") for (int nd_ = 0; nd_ < 8; ++nd_)                        \
        vv[nd_] = *(const bf16x8*)(vp_ + (size_t)nd_ * 16 * SEQ);              \
  } while (0)

#define COMPUTE(kreg, kt_)                                                     \
  do {                                                                         \
    const int k0_ = (kt_) * 32;                                                \
    f32x4 sc[2] = {};                                                          \
    __builtin_amdgcn_s_setprio(1);                                             \
    _Pragma("unroll") for (int n0_ = 0; n0_ < 2; ++n0_)                        \
        _Pragma("unroll") for (int c_ = 0; c_ < 6; ++c_)                       \
            sc[n0_] = __builtin_amdgcn_mfma_f32_16x16x32_bf16(                 \
        qfr[c_], kreg[n0_ * 6 + c_], sc[n0_], 0, 0, 0);                        \
    __builtin_amdgcn_s_setprio(0);                                             \
    float s0a[4], s1a[4];                                                      \
    float over = -1e30f;                                                       \
    {                                                                          \
      const int kc0 = k0_ + lm, kc1 = k0_ + 16 + lm;                           \
      _Pragma("unroll") for (int r = 0; r < 4; ++r) {                          \
        s0a[r] = (kc0 <= qrow[r]) ? sc[0][r] : -1e30f;                         \
        s1a[r] = (kc1 <= qrow[r]) ? sc[1][r] : -1e30f;                         \
        over = fmaxf(over, fmaxf(s0a[r], s1a[r]) - m_r[r]);                    \
      }                                                                        \
    }                                                                          \
    if (__any(over > 8.0f)) {                                                  \
      _Pragma("unroll") for (int r = 0; r < 4; ++r) {                          \
        float mx = fmaxf(s0a[r], s1a[r]);                                      \
        _Pragma("unroll") for (int md = 1; md < 16; md <<= 1)                  \
            mx = fmaxf(mx, __shfl_xor(mx, md, 64));                            \
        float mnew = fmaxf(m_r[r], mx);                                        \
        float alpha = __expf(m_r[r] - mnew);                                   \
        m_r[r] = mnew;                                                         \
        l_loc[r] *= alpha;                                                     \
        _Pragma("unroll") for (int nd = 0; nd < 8; ++nd) oacc[nd][r] *= alpha; \
      }                                                                        \
    }                                                                          \
    _Pragma("unroll") for (int r = 0; r < 4; ++r) {                            \
      float p0 = __expf(s0a[r] - m_r[r]);                                      \
      float p1 = __expf(s1a[r] - m_r[r]);                                      \
      l_loc[r] += p0 + p1;                                                     \
      p_lds[lg * 4 + r][lm] = f2bf(p0);                                        \
      p_lds[lg * 4 + r][16 + lm] = f2bf(p1);                                   \
    }                                                                          \
    asm volatile("s_waitcnt lgkmcnt(0)" ::: "memory");                         \
    __builtin_amdgcn_sched_barrier(0);                                         \
    bf16x8 pa = *(const bf16x8*)(&p_lds[lm][lg * 8]);                          \
    __builtin_amdgcn_s_setprio(1);                                             \
    _Pragma("unroll") for (int nd = 0; nd < 8; ++nd)                           \
        oacc[nd] =                                                             \
        __builtin_amdgcn_mfma_f32_16x16x32_bf16(pa, vv[nd], oacc[nd], 0, 0, 0);\
    __builtin_amdgcn_s_setprio(0);                                             \
  } while (0)

  LOADK(kA, kt);
  for (;;) {
    LOADV(kt);                           // V first: PV's vmcnt wait keeps
    if (kt + 1 < ktN) LOADK(kB, kt + 1); // next-K prefetch in flight
    COMPUTE(kA, kt);
    ++kt;
    if (kt >= ktN) break;
    LOADV(kt);
    if (kt + 1 < ktN) LOADK(kA, kt + 1);
    COMPUTE(kB, kt);
    ++kt;
    if (kt >= ktN) break;
  }
#undef LOADK
#undef LOADV
#undef COMPUTE

  float l_row[4];
#pragma unroll
  for (int r = 0; r < 4; ++r) {
    float lt = l_loc[r];
#pragma unroll
    for (int md = 1; md < 16; md <<= 1) lt += __shfl_xor(lt, md, 64);
    l_row[r] = lt;
  }
  if (nc == 1) {
#pragma unroll
    for (int r = 0; r < 4; ++r) {
      float inv = 1.0f / l_row[r];
#pragma unroll
      for (int nd = 0; nd < 8; ++nd)
        attn_out[(size_t)qrow[r] * (NH * DV) + h * DV + nd * 16 + lm] =
            f2bf(oacc[nd][r] * inv);
    }
  } else {
    float* op = O_part + (size_t)bid * 2048;
#pragma unroll
    for (int r = 0; r < 4; ++r) {
#pragma unroll
      for (int nd = 0; nd < 8; ++nd)
        op[(lg * 4 + r) * 128 + nd * 16 + lm] = oacc[nd][r];
      if (lm == 0) {
        mlbuf[bid * 32 + lg * 4 + r] = m_r[r];
        mlbuf[bid * 32 + 16 + lg * 4 + r] = l_row[r];
      }
    }
  }
}

// ---------------- merge split-K partials ----------------
__global__ __launch_bounds__(64) void k_merge(const float* __restrict__ O_part,
                                              const float* __restrict__ mlbuf,
                                              u16* __restrict__ attn_out) {
  const int b = blockIdx.x;            // [0, 1536)
  const int h = b & 15, rest = b >> 4; // rest in [0,96)
  const int seg = rest >= 48;
  const int j = (rest - seg * 48) + 16;
  const int nc = (j >= 48) ? 4 : (j >= 32) ? 3 : 2;
  const int x = h >> 1, hh = h & 1;
  const int vbase = (j >= 48) ? (j - 48) * 4
                  : (j >= 32) ? 64 + (j - 32) * 3
                              : 112 + (j - 16) * 2;
  const int lane = threadIdx.x;
  const int row = lane >> 2, cg = lane & 3;

  int tid[4];
  float mv[4], lv[4], wgt[4];
  float M = -1e30f;
  for (int cc = 0; cc < nc; ++cc) {
    tid[cc] = ((seg * 160 + vbase + cc) * 2 + hh) * 8 + x;
    mv[cc] = mlbuf[tid[cc] * 32 + row];
    lv[cc] = mlbuf[tid[cc] * 32 + 16 + row];
    M = fmaxf(M, mv[cc]);
  }
  float lt = 0.f;
  for (int cc = 0; cc < nc; ++cc) { wgt[cc] = __expf(mv[cc] - M); lt += wgt[cc] * lv[cc]; }
  const float inv = 1.0f / lt;
  const int qrow = ((seg * 64 + j) * 16) + row;
  u16* dst = attn_out + (size_t)qrow * (NH * DV) + h * DV + cg * 32;
#pragma unroll
  for (int e = 0; e < 32; e += 4) {
    float a0 = 0, a1 = 0, a2 = 0, a3 = 0;
    for (int cc = 0; cc < nc; ++cc) {
      const float4 p = *(const float4*)(O_part + (size_t)tid[cc] * 2048 + row * 128 + cg * 32 + e);
      a0 += wgt[cc] * p.x; a1 += wgt[cc] * p.y; a2 += wgt[cc] * p.z; a3 += wgt[cc] * p.w;
    }
    dst[e] = f2bf(a0 * inv); dst[e + 1] = f2bf(a1 * inv);
    dst[e + 2] = f2bf(a2 * inv); dst[e + 3] = f2bf(a3 * inv);
  }
}

extern "C" void kernel_launch(void* const* d_in, const int* in_sizes, int n_in,
                              void* d_out, int out_size, void* d_ws, size_t ws_size,
                              hipStream_t stream) {
  const float* hs = (const float*)d_in[0];
  const float* cosb = (const float*)d_in[1];
  const float* sinb = (const float*)d_in[2];
  const float* wq_a = (const float*)d_in[3];
  const float* q_a_ln_w = (const float*)d_in[4];
  const float* wq_b = (const float*)d_in[5];
  const float* wkv_a = (const float*)d_in[6];
  const float* kv_a_ln_w = (const float*)d_in[7];
  const float* wkv_b = (const float*)d_in[8];
  const float* wo = (const float*)d_in[9];

  char* ws = (char*)d_ws;
  size_t off = 0;
  auto take = [&](size_t bytes) {
    size_t o = off;
    off += (bytes + 255) & ~(size_t)255;
    return o;
  };
  u16* hs_bf = (u16*)(ws + take((size_t)SEQ * HID * 2));
  u16* wqkva = (u16*)(ws + take((size_t)NKVA * HID * 2));
  u16* wqb = (u16*)(ws + take((size_t)(NH * DQK) * QLR * 2));
  u16* wkvb = (u16*)(ws + take((size_t)(NH * 256) * KVLR * 2));
  u16* wo_bf = (u16*)(ws + take((size_t)HID * (NH * DV) * 2));
  // --- group A: dead before k_attn; re-used as split-K partial storage ---
  const size_t scratch0 = off;
  float* qkva = (float*)(ws + take((size_t)SEQ * NKVA * 4));
  u16* q_ln = (u16*)(ws + take((size_t)SEQ * QLR * 2));
  u16* kv_ln = (u16*)(ws + take((size_t)SEQ * KVLR * 2));
  u16* qfull = (u16*)(ws + take((size_t)SEQ * NH * DQK * 2));
  u16* kvfull = (u16*)(ws + take((size_t)SEQ * NH * 256 * 2));
  // group A = ~55.6 MB >= O_part(41.9) + ml(0.7)
  float* O_part = (float*)(ws + scratch0);
  float* mlbuf = (float*)(ws + scratch0 + (size_t)NTASK * 2048 * 4);
  // --- group B: live across k_attn ---
  u16* qf = (u16*)(ws + take((size_t)NH * SEQ * DQK * 2));
  u16* kf = (u16*)(ws + take((size_t)NH * SEQ * DQK * 2));
  u16* vt = (u16*)(ws + take((size_t)NH * DV * SEQ * 2));
  u16* attn = (u16*)(ws + take((size_t)SEQ * NH * DV * 2));
  if (off > ws_size) return;

  auto blocks4 = [](long n) {
    long b = (n / 4 + 255) / 256;
    return (int)(b > 4096 ? 4096 : b);
  };

  k_convert<<<blocks4((long)SEQ * HID), 256, 0, stream>>>(hs, hs_bf, (long)SEQ * HID, (long)SEQ * HID);
  k_convert<<<blocks4((long)QLR * HID), 256, 0, stream>>>(wq_a, wqkva, (long)QLR * HID, (long)QLR * HID);
  k_convert<<<blocks4((long)640 * HID), 256, 0, stream>>>(wkv_a, wqkva + (size_t)QLR * HID,
                                                          (long)(KVLR + DR) * HID, (long)640 * HID);
  k_convert<<<blocks4((long)NH * DQK * QLR), 256, 0, stream>>>(wq_b, wqb, (long)NH * DQK * QLR,
                                                               (long)NH * DQK * QLR);
  k_convert<<<blocks4((long)NH * 256 * KVLR), 256, 0, stream>>>(wkv_b, wkvb, (long)NH * 256 * KVLR,
                                                                (long)NH * 256 * KVLR);
  k_convert<<<blocks4((long)HID * NH * DV), 256, 0, stream>>>(wo, wo_bf, (long)HID * NH * DV,
                                                              (long)HID * NH * DV);

  dim3 g1(NKVA / 128, SEQ / 128);
  k_gemm_nt<<<g1, 256, 0, stream>>>(hs_bf, wqkva, qkva, SEQ, NKVA, HID, 0);

  k_rmsnorm<<<SEQ, 256, 0, stream>>>(qkva, q_a_ln_w, q_ln, NKVA, QLR, 1.0f / QLR);
  k_rmsnorm<<<SEQ, 256, 0, stream>>>(qkva + QLR, kv_a_ln_w, kv_ln, NKVA, KVLR, 1.0f / KVLR);

  dim3 g2(NH * DQK / 128, SEQ / 128);
  k_gemm_nt<<<g2, 256, 0, stream>>>(q_ln, wqb, qfull, SEQ, NH * DQK, QLR, 1);
  dim3 g3(NH * 256 / 128, SEQ / 128);
  k_gemm_nt<<<g3, 256, 0, stream>>>(kv_ln, wkvb, kvfull, SEQ, NH * 256, KVLR, 1);

  k_mk_qf<<<dim3(SEQ, NH), 128, 0, stream>>>(qfull, cosb, sinb, qf);
  k_mk_kf_v<<<dim3(SEQ, NH), 128, 0, stream>>>(kvfull, qkva + (QLR + KVLR), NKVA, cosb, sinb, kf, vt);

  k_attn<<<NTASK, 64, 0, stream>>>(qf, kf, vt, attn, O_part, mlbuf);
  k_merge<<<NMERGE, 64, 0, stream>>>(O_part, mlbuf, attn);

  dim3 g4(HID / 128, SEQ / 128);
  k_gemm_nt<<<g4, 256, 0, stream>>>(attn, wo_bf, d_out, SEQ, HID, NH * DV, 0);
}

// Round 5
// 273.888 us; speedup vs baseline: 1.2950x; 1.2950x over previous
//
#include <hip/hip_runtime.h>

typedef unsigned short u16;
typedef __attribute__((ext_vector_type(8))) short bf16x8;
typedef __attribute__((ext_vector_type(4))) float f32x4;

#define HID 2048
#define NH 16
#define QLR 1536
#define KVLR 512
#define DR 64
#define DN 128
#define DQK 192
#define DV 128
#define SEQ 2048
#define NKVA 2176
#define SCALE 0.07216878364870323f  // 192^-0.5

static __device__ __forceinline__ u16 f2bf(float f) {
  unsigned v = __builtin_bit_cast(unsigned, f);
  v = v + 0x7fffu + ((v >> 16) & 1u);
  return (u16)(v >> 16);
}
static __device__ __forceinline__ float bf2f(u16 u) {
  unsigned v = ((unsigned)u) << 16;
  return __builtin_bit_cast(float, v);
}

#define GLOAD16(gp, lp)                                                        \
  __builtin_amdgcn_global_load_lds(                                            \
      (const __attribute__((address_space(1))) void*)(gp),                     \
      (__attribute__((address_space(3))) void*)(lp), 16, 0, 0)

// ---------------- f32 -> bf16 convert; trailing region (i >= nsrc) zeroed ----
__global__ void k_convert(const float* __restrict__ src, u16* __restrict__ dst,
                          long nsrc, long ndst) {
  long i = ((long)blockIdx.x * blockDim.x + threadIdx.x) * 4;
  long stride = (long)gridDim.x * blockDim.x * 4;
  for (; i < ndst; i += stride) {
    u16 o0 = 0, o1 = 0, o2 = 0, o3 = 0;
    if (i < nsrc) {
      const float4 f = *(const float4*)(src + i);
      o0 = f2bf(f.x); o1 = f2bf(f.y); o2 = f2bf(f.z); o3 = f2bf(f.w);
    }
    u16* d = dst + i;
    d[0] = o0; d[1] = o1; d[2] = o2; d[3] = o3;
  }
}

// ---------------- row RMSNorm ----------------
__global__ void k_rmsnorm(const float* __restrict__ X, const float* __restrict__ w,
                          u16* __restrict__ Y, int xstride, int cols, float inv_cols) {
  const int row = blockIdx.x;
  const int t = threadIdx.x;
  const float* x = X + (size_t)row * xstride;
  float ss = 0.f;
  for (int i = t * 4; i < cols; i += 1024) {
    float4 v = *(const float4*)(x + i);
    ss += v.x * v.x + v.y * v.y + v.z * v.z + v.w * v.w;
  }
#pragma unroll
  for (int m = 1; m < 64; m <<= 1) ss += __shfl_xor(ss, m, 64);
  __shared__ float red[4];
  if ((t & 63) == 0) red[t >> 6] = ss;
  __syncthreads();
  float tot = red[0] + red[1] + red[2] + red[3];
  float r = rsqrtf(tot * inv_cols + 1e-6f);
  for (int i = t * 4; i < cols; i += 1024) {
    float4 v = *(const float4*)(x + i);
    float4 g = *(const float4*)(w + i);
    u16* y = Y + (size_t)row * cols + i;
    y[0] = f2bf(v.x * r * g.x);
    y[1] = f2bf(v.y * r * g.y);
    y[2] = f2bf(v.z * r * g.z);
    y[3] = f2bf(v.w * r * g.w);
  }
}

// ---------------- NT GEMM (m97-style 128x128, XCD swizzle) ----------------
__global__ __launch_bounds__(256) void k_gemm_nt(
    const u16* __restrict__ A, const u16* __restrict__ B, void* __restrict__ Cout,
    int M, int N, int K, int c_bf16) {
  __shared__ __align__(16) u16 As[4096];
  __shared__ __align__(16) u16 Bs[4096];
  const int t = threadIdx.x;
  const int lane = t & 63;
  const int w = t >> 6, wr = w >> 1, wc = w & 1;
  const int lm = lane & 15, lg = lane >> 4;

  const int nwg = gridDim.x * gridDim.y;
  int bid = blockIdx.y * gridDim.x + blockIdx.x;
  if ((nwg & 7) == 0) bid = (bid & 7) * (nwg >> 3) + (bid >> 3);
  const int bm = bid % gridDim.y;
  const int bn = bid / gridDim.y;

  const u16* a0 = A + (size_t)(bm * 128 + (t >> 2)) * K + (t & 3) * 8;
  const u16* b0 = B + (size_t)(bn * 128 + (t >> 2)) * K + (t & 3) * 8;
  const size_t rK = (size_t)64 * K;
  u16* as0 = As + t * 8;
  u16* bs0 = Bs + t * 8;

  f32x4 acc[4][4] = {};
  for (int kt = 0; kt < K; kt += 32) {
    GLOAD16(a0 + kt, as0);
    GLOAD16(a0 + rK + kt, as0 + 2048);
    GLOAD16(b0 + kt, bs0);
    GLOAD16(b0 + rK + kt, bs0 + 2048);
    __syncthreads();
    bf16x8 af[4], bfr[4];
#pragma unroll
    for (int i = 0; i < 4; ++i)
      af[i] = *(const bf16x8*)(As + (wr * 64 + i * 16 + lm) * 32 + lg * 8);
#pragma unroll
    for (int j = 0; j < 4; ++j)
      bfr[j] = *(const bf16x8*)(Bs + (wc * 64 + j * 16 + lm) * 32 + lg * 8);
#pragma unroll
    for (int i = 0; i < 4; ++i)
#pragma unroll
      for (int j = 0; j < 4; ++j)
        acc[i][j] = __builtin_amdgcn_mfma_f32_16x16x32_bf16(af[i], bfr[j], acc[i][j], 0, 0, 0);
    __syncthreads();
  }
  const int row0 = bm * 128 + wr * 64 + lg * 4;
  const int col0 = bn * 128 + wc * 64 + lm;
  if (c_bf16) {
    u16* C = (u16*)Cout;
#pragma unroll
    for (int i = 0; i < 4; ++i)
#pragma unroll
      for (int r = 0; r < 4; ++r) {
        u16* crow = C + (size_t)(row0 + i * 16 + r) * N + col0;
#pragma unroll
        for (int j = 0; j < 4; ++j) crow[j * 16] = f2bf(acc[i][j][r]);
      }
  } else {
    float* C = (float*)Cout;
#pragma unroll
    for (int i = 0; i < 4; ++i)
#pragma unroll
      for (int r = 0; r < 4; ++r) {
        float* crow = C + (size_t)(row0 + i * 16 + r) * N + col0;
#pragma unroll
        for (int j = 0; j < 4; ++j) crow[j * 16] = acc[i][j][r];
      }
  }
}

// ------- assemble qf (pre-scaled) ----------
__global__ void k_mk_qf(const u16* __restrict__ qfull, const float* __restrict__ cosb,
                        const float* __restrict__ sinb, u16* __restrict__ qf) {
  const int s = blockIdx.x, h = blockIdx.y, t = threadIdx.x;
  const u16* src = qfull + (size_t)s * (NH * DQK) + h * DQK;
  u16* dst = qf + ((size_t)h * SEQ + s) * DQK;
  dst[t] = f2bf(bf2f(src[t]) * SCALE);
  if (t < 32) {
    float a = bf2f(src[DN + 2 * t]);
    float b = bf2f(src[DN + 2 * t + 1]);
    float c = cosb[(size_t)s * DR + t];
    float sn = sinb[(size_t)s * DR + t];
    dst[DN + t] = f2bf((a * c - b * sn) * SCALE);
    dst[DN + 32 + t] = f2bf((b * c + a * sn) * SCALE);
  }
}

// -------- assemble kf and v_t[h][d][s] --------
__global__ void k_mk_kf_v(const u16* __restrict__ kvfull, const float* __restrict__ krot,
                          int krot_stride, const float* __restrict__ cosb,
                          const float* __restrict__ sinb, u16* __restrict__ kf,
                          u16* __restrict__ vt) {
  const int s = blockIdx.x, h = blockIdx.y, t = threadIdx.x;
  const u16* src = kvfull + (size_t)s * (NH * 256) + h * 256;
  u16* kdst = kf + ((size_t)h * SEQ + s) * DQK;
  kdst[t] = src[t];
  vt[((size_t)h * DV + t) * SEQ + s] = src[DN + t];
  if (t < 32) {
    float a = krot[(size_t)s * krot_stride + 2 * t];
    float b = krot[(size_t)s * krot_stride + 2 * t + 1];
    float c = cosb[(size_t)s * DR + t];
    float sn = sinb[(size_t)s * DR + t];
    kdst[DN + t] = f2bf(a * c - b * sn);
    kdst[DN + 32 + t] = f2bf(b * c + a * sn);
  }
}

// ---------------- flash attention v5: cooperative LDS-staged blocks ----------
// block = 64 q-rows x 4 waves (16 rows each), KVBLK=32. K/V tiles staged
// into LDS via global_load_lds (linear dest, XOR-swizzled global source;
// swizzled ds_read). Double-buffered, stage-before-compute, one barrier/iter.
// 512 blocks; heads pinned 2/XCD via bid&7; longest tiles first.
// Segments hardcoded [0,1024,2048] (fixed by setup_inputs).
__global__ __launch_bounds__(256) void k_attn(
    const u16* __restrict__ qf, const u16* __restrict__ kf, const u16* __restrict__ vt,
    u16* __restrict__ attn_out) {
  __shared__ __align__(16) u16 Ks[2][32 * 192];   // [kv][k-dim], swizzled
  __shared__ __align__(16) u16 Vs[2][128 * 32];   // [d][kv], swizzled
  __shared__ __align__(16) u16 p_lds[4][16][32];

  const int t = threadIdx.x, lane = t & 63, w = t >> 6;
  const int lm = lane & 15, lg = lane >> 4;
  const int bid = blockIdx.x;
  const int x = bid & 7, r0 = bid >> 3;  // r0 in [0,64)
  const int h = x * 2 + (r0 & 1);        // 2 heads per XCD
  const int u = r0 >> 1;                 // [0,32)
  const int seg = u & 1;
  const int tj = 15 - (u >> 1);          // [0,16) longest first
  const int tile_row0 = seg * 1024 + tj * 64;
  const int k_begin = seg * 1024;
  const int n_kt = tj * 2 + 2;

  // per-wave Q fragments (pre-scaled): rows tile_row0 + w*16 + lm
  const int lo_row = tile_row0 + w * 16;
  bf16x8 qfr[6];
  {
    const u16* qp = qf + ((size_t)h * SEQ + (lo_row + lm)) * DQK + lg * 8;
#pragma unroll
    for (int c = 0; c < 6; ++c) qfr[c] = *(const bf16x8*)(qp + c * 32);
  }
  int qrow[4];
#pragma unroll
  for (int r = 0; r < 4; ++r) qrow[r] = lo_row + lg * 4 + r;

  float m_r[4], l_loc[4];
#pragma unroll
  for (int r = 0; r < 4; ++r) { m_r[r] = -3.0e4f; l_loc[r] = 0.f; }
  f32x4 oacc[8] = {};

  // stage K tile (32x192, 3 passes) + V tile (128x32, 2 passes) into buf.
  // LDS dest linear in thread id; global col index inverse-XOR-swizzled.
#define STAGE(buf, kt_)                                                        \
  do {                                                                         \
    const int k0_ = k_begin + (kt_) * 32;                                      \
    _Pragma("unroll") for (int p = 0; p < 3; ++p) {                            \
      const int id = p * 256 + t;                                              \
      const int row = id / 24, colL = id - row * 24;                           \
      const u16* g = kf + ((size_t)h * SEQ + k0_ + row) * DQK +                \
                     ((colL ^ (row & 7)) * 8);                                 \
      GLOAD16(g, (u16*)Ks[buf] + id * 8);                                      \
    }                                                                          \
    _Pragma("unroll") for (int p = 0; p < 2; ++p) {                            \
      const int id = p * 256 + t;                                              \
      const int row = id >> 2, colL = id & 3;                                  \
      const u16* g = vt + ((size_t)h * DV + row) * SEQ + k0_ +                 \
                     ((colL ^ (row & 3)) * 8);                                 \
      GLOAD16(g, (u16*)Vs[buf] + id * 8);                                      \
    }                                                                          \
  } while (0)

#define COMPUTE(buf, kt_)                                                      \
  do {                                                                         \
    const int k0_ = k_begin + (kt_) * 32;                                      \
    f32x4 sc[2] = {};                                                          \
    _Pragma("unroll") for (int n0_ = 0; n0_ < 2; ++n0_)                        \
        _Pragma("unroll") for (int c_ = 0; c_ < 6; ++c_) {                     \
      const int row_ = n0_ * 16 + lm, cc_ = c_ * 4 + lg;                       \
      bf16x8 kfr = *(const bf16x8*)(Ks[buf] + row_ * 192 +                     \
                                    ((cc_ ^ (row_ & 7)) * 8));                 \
      sc[n0_] = __builtin_amdgcn_mfma_f32_16x16x32_bf16(qfr[c_], kfr,          \
                                                        sc[n0_], 0, 0, 0);     \
    }                                                                          \
    float s0a[4], s1a[4];                                                      \
    float over = -1e30f;                                                       \
    {                                                                          \
      const int kc0 = k0_ + lm, kc1 = k0_ + 16 + lm;                           \
      _Pragma("unroll") for (int r = 0; r < 4; ++r) {                          \
        s0a[r] = (kc0 <= qrow[r]) ? sc[0][r] : -1e30f;                         \
        s1a[r] = (kc1 <= qrow[r]) ? sc[1][r] : -1e30f;                         \
        over = fmaxf(over, fmaxf(s0a[r], s1a[r]) - m_r[r]);                    \
      }                                                                        \
    }                                                                          \
    if (__any(over > 8.0f)) {                                                  \
      _Pragma("unroll") for (int r = 0; r < 4; ++r) {                          \
        float mx = fmaxf(s0a[r], s1a[r]);                                      \
        _Pragma("unroll") for (int md = 1; md < 16; md <<= 1)                  \
            mx = fmaxf(mx, __shfl_xor(mx, md, 64));                            \
        float mnew = fmaxf(m_r[r], mx);                                        \
        float alpha = __expf(m_r[r] - mnew);                                   \
        m_r[r] = mnew;                                                         \
        l_loc[r] *= alpha;                                                     \
        _Pragma("unroll") for (int nd = 0; nd < 8; ++nd) oacc[nd][r] *= alpha; \
      }                                                                        \
    }                                                                          \
    _Pragma("unroll") for (int r = 0; r < 4; ++r) {                            \
      float p0 = __expf(s0a[r] - m_r[r]);                                      \
      float p1 = __expf(s1a[r] - m_r[r]);                                      \
      l_loc[r] += p0 + p1;                                                     \
      p_lds[w][lg * 4 + r][lm] = f2bf(p0);                                     \
      p_lds[w][lg * 4 + r][16 + lm] = f2bf(p1);                                \
    }                                                                          \
    asm volatile("s_waitcnt lgkmcnt(0)" ::: "memory");                         \
    __builtin_amdgcn_sched_barrier(0);                                         \
    bf16x8 pa = *(const bf16x8*)(&p_lds[w][lm][lg * 8]);                       \
    _Pragma("unroll") for (int nd = 0; nd < 8; ++nd) {                         \
      const int row_ = nd * 16 + lm;                                           \
      bf16x8 vvf = *(const bf16x8*)(Vs[buf] + row_ * 32 +                      \
                                    ((lg ^ (row_ & 3)) * 8));                  \
      oacc[nd] =                                                               \
          __builtin_amdgcn_mfma_f32_16x16x32_bf16(pa, vvf, oacc[nd], 0, 0, 0); \
    }                                                                          \
  } while (0)

  int cur = 0;
  STAGE(0, 0);
  __syncthreads();
  for (int kt = 0;;) {
    if (kt + 1 < n_kt) STAGE(cur ^ 1, kt + 1);  // loads fly under compute
    COMPUTE(cur, kt);
    ++kt;
    if (kt >= n_kt) break;
    __syncthreads();  // next buffer staged + everyone done with cur
    cur ^= 1;
  }
#undef STAGE
#undef COMPUTE

#pragma unroll
  for (int r = 0; r < 4; ++r) {
    float lt = l_loc[r];
#pragma unroll
    for (int md = 1; md < 16; md <<= 1) lt += __shfl_xor(lt, md, 64);
    float inv = 1.0f / lt;
#pragma unroll
    for (int nd = 0; nd < 8; ++nd)
      attn_out[(size_t)qrow[r] * (NH * DV) + h * DV + nd * 16 + lm] =
          f2bf(oacc[nd][r] * inv);
  }
}

extern "C" void kernel_launch(void* const* d_in, const int* in_sizes, int n_in,
                              void* d_out, int out_size, void* d_ws, size_t ws_size,
                              hipStream_t stream) {
  const float* hs = (const float*)d_in[0];
  const float* cosb = (const float*)d_in[1];
  const float* sinb = (const float*)d_in[2];
  const float* wq_a = (const float*)d_in[3];
  const float* q_a_ln_w = (const float*)d_in[4];
  const float* wq_b = (const float*)d_in[5];
  const float* wkv_a = (const float*)d_in[6];
  const float* kv_a_ln_w = (const float*)d_in[7];
  const float* wkv_b = (const float*)d_in[8];
  const float* wo = (const float*)d_in[9];

  char* ws = (char*)d_ws;
  size_t off = 0;
  auto take = [&](size_t bytes) {
    size_t o = off;
    off += (bytes + 255) & ~(size_t)255;
    return o;
  };
  u16* hs_bf = (u16*)(ws + take((size_t)SEQ * HID * 2));
  u16* wqkva = (u16*)(ws + take((size_t)NKVA * HID * 2));
  u16* wqb = (u16*)(ws + take((size_t)(NH * DQK) * QLR * 2));
  u16* wkvb = (u16*)(ws + take((size_t)(NH * 256) * KVLR * 2));
  u16* wo_bf = (u16*)(ws + take((size_t)HID * (NH * DV) * 2));
  float* qkva = (float*)(ws + take((size_t)SEQ * NKVA * 4));
  u16* q_ln = (u16*)(ws + take((size_t)SEQ * QLR * 2));
  u16* kv_ln = (u16*)(ws + take((size_t)SEQ * KVLR * 2));
  u16* qfull = (u16*)(ws + take((size_t)SEQ * NH * DQK * 2));
  u16* kvfull = (u16*)(ws + take((size_t)SEQ * NH * 256 * 2));
  u16* qf = (u16*)(ws + take((size_t)NH * SEQ * DQK * 2));
  u16* kf = (u16*)(ws + take((size_t)NH * SEQ * DQK * 2));
  u16* vt = (u16*)(ws + take((size_t)NH * DV * SEQ * 2));
  u16* attn = (u16*)(ws + take((size_t)SEQ * NH * DV * 2));
  if (off > ws_size) return;

  auto blocks4 = [](long n) {
    long b = (n / 4 + 255) / 256;
    return (int)(b > 4096 ? 4096 : b);
  };

  k_convert<<<blocks4((long)SEQ * HID), 256, 0, stream>>>(hs, hs_bf, (long)SEQ * HID, (long)SEQ * HID);
  k_convert<<<blocks4((long)QLR * HID), 256, 0, stream>>>(wq_a, wqkva, (long)QLR * HID, (long)QLR * HID);
  k_convert<<<blocks4((long)640 * HID), 256, 0, stream>>>(wkv_a, wqkva + (size_t)QLR * HID,
                                                          (long)(KVLR + DR) * HID, (long)640 * HID);
  k_convert<<<blocks4((long)NH * DQK * QLR), 256, 0, stream>>>(wq_b, wqb, (long)NH * DQK * QLR,
                                                               (long)NH * DQK * QLR);
  k_convert<<<blocks4((long)NH * 256 * KVLR), 256, 0, stream>>>(wkv_b, wkvb, (long)NH * 256 * KVLR,
                                                                (long)NH * 256 * KVLR);
  k_convert<<<blocks4((long)HID * NH * DV), 256, 0, stream>>>(wo, wo_bf, (long)HID * NH * DV,
                                                              (long)HID * NH * DV);

  dim3 g1(NKVA / 128, SEQ / 128);
  k_gemm_nt<<<g1, 256, 0, stream>>>(hs_bf, wqkva, qkva, SEQ, NKVA, HID, 0);

  k_rmsnorm<<<SEQ, 256, 0, stream>>>(qkva, q_a_ln_w, q_ln, NKVA, QLR, 1.0f / QLR);
  k_rmsnorm<<<SEQ, 256, 0, stream>>>(qkva + QLR, kv_a_ln_w, kv_ln, NKVA, KVLR, 1.0f / KVLR);

  dim3 g2(NH * DQK / 128, SEQ / 128);
  k_gemm_nt<<<g2, 256, 0, stream>>>(q_ln, wqb, qfull, SEQ, NH * DQK, QLR, 1);
  dim3 g3(NH * 256 / 128, SEQ / 128);
  k_gemm_nt<<<g3, 256, 0, stream>>>(kv_ln, wkvb, kvfull, SEQ, NH * 256, KVLR, 1);

  k_mk_qf<<<dim3(SEQ, NH), 128, 0, stream>>>(qfull, cosb, sinb, qf);
  k_mk_kf_v<<<dim3(SEQ, NH), 128, 0, stream>>>(kvfull, qkva + (QLR + KVLR), NKVA, cosb, sinb, kf, vt);

  k_attn<<<512, 256, 0, stream>>>(qf, kf, vt, attn);

  dim3 g4(HID / 128, SEQ / 128);
  k_gemm_nt<<<g4, 256, 0, stream>>>(attn, wo_bf, d_out, SEQ, HID, NH * DV, 0);
}

// Round 6
// 237.799 us; speedup vs baseline: 1.4915x; 1.1518x over previous
//
#include <hip/hip_runtime.h>

typedef unsigned short u16;
typedef __attribute__((ext_vector_type(8))) short bf16x8;
typedef __attribute__((ext_vector_type(4))) float f32x4;

#define HID 2048
#define NH 16
#define QLR 1536
#define KVLR 512
#define DR 64
#define DN 128
#define DQK 192
#define DV 128
#define SEQ 2048
#define NKVA 2176
#define SCALE 0.07216878364870323f  // 192^-0.5

static __device__ __forceinline__ u16 f2bf(float f) {
  unsigned v = __builtin_bit_cast(unsigned, f);
  v = v + 0x7fffu + ((v >> 16) & 1u);
  return (u16)(v >> 16);
}
static __device__ __forceinline__ float bf2f(u16 u) {
  unsigned v = ((unsigned)u) << 16;
  return __builtin_bit_cast(float, v);
}

#define GLOAD16(gp, lp)                                                        \
  __builtin_amdgcn_global_load_lds(                                            \
      (const __attribute__((address_space(1))) void*)(gp),                     \
      (__attribute__((address_space(3))) void*)(lp), 16, 0, 0)

// ---------------- f32 -> bf16 convert; trailing region (i >= nsrc) zeroed ----
__global__ void k_convert(const float* __restrict__ src, u16* __restrict__ dst,
                          long nsrc, long ndst) {
  long i = ((long)blockIdx.x * blockDim.x + threadIdx.x) * 4;
  long stride = (long)gridDim.x * blockDim.x * 4;
  for (; i < ndst; i += stride) {
    u16 o0 = 0, o1 = 0, o2 = 0, o3 = 0;
    if (i < nsrc) {
      const float4 f = *(const float4*)(src + i);
      o0 = f2bf(f.x); o1 = f2bf(f.y); o2 = f2bf(f.z); o3 = f2bf(f.w);
    }
    u16* d = dst + i;
    d[0] = o0; d[1] = o1; d[2] = o2; d[3] = o3;
  }
}

// ---------------- row RMSNorm ----------------
__global__ void k_rmsnorm(const float* __restrict__ X, const float* __restrict__ w,
                          u16* __restrict__ Y, int xstride, int cols, float inv_cols) {
  const int row = blockIdx.x;
  const int t = threadIdx.x;
  const float* x = X + (size_t)row * xstride;
  float ss = 0.f;
  for (int i = t * 4; i < cols; i += 1024) {
    float4 v = *(const float4*)(x + i);
    ss += v.x * v.x + v.y * v.y + v.z * v.z + v.w * v.w;
  }
#pragma unroll
  for (int m = 1; m < 64; m <<= 1) ss += __shfl_xor(ss, m, 64);
  __shared__ float red[4];
  if ((t & 63) == 0) red[t >> 6] = ss;
  __syncthreads();
  float tot = red[0] + red[1] + red[2] + red[3];
  float r = rsqrtf(tot * inv_cols + 1e-6f);
  for (int i = t * 4; i < cols; i += 1024) {
    float4 v = *(const float4*)(x + i);
    float4 g = *(const float4*)(w + i);
    u16* y = Y + (size_t)row * cols + i;
    y[0] = f2bf(v.x * r * g.x);
    y[1] = f2bf(v.y * r * g.y);
    y[2] = f2bf(v.z * r * g.z);
    y[3] = f2bf(v.w * r * g.w);
  }
}

// ---------------- NT GEMM v2: 128x128 tile, BK=64, double-buffered LDS ------
// 2-phase per K-step: STAGE(next) -> ds_read+MFMA(cur) -> __syncthreads.
// T2 XOR swizzle: linear gload_lds dest, inverse-swizzled global source,
// swizzled ds_read (rule #21). XCD-bijective block swizzle.
__global__ __launch_bounds__(256) void k_gemm_nt(
    const u16* __restrict__ A, const u16* __restrict__ B, void* __restrict__ Cout,
    int M, int N, int K, int c_bf16) {
  __shared__ __align__(16) u16 As[2][8192];   // [buf][128 rows x 64 cols]
  __shared__ __align__(16) u16 Bs[2][8192];
  const int t = threadIdx.x;
  const int lane = t & 63;
  const int w = t >> 6, wr = w >> 1, wc = w & 1;
  const int lm = lane & 15, lg = lane >> 4;

  const int nwg = gridDim.x * gridDim.y;
  int bid = blockIdx.y * gridDim.x + blockIdx.x;
  if ((nwg & 7) == 0) bid = (bid & 7) * (nwg >> 3) + (bid >> 3);
  const int bm = bid % gridDim.y;
  const int bn = bid / gridDim.y;

  // staging addresses: thread t covers row (p*32 + t>>3), 16B slot (t&7),
  // global slot pre-swizzled so LDS[row][s] holds global slot s^(row&7)
  const int srow = t >> 3;
  const int scol = ((t & 7) ^ (srow & 7)) * 8;
  const u16* aBase = A + (size_t)(bm * 128 + srow) * K + scol;
  const u16* bBase = B + (size_t)(bn * 128 + srow) * K + scol;
  const size_t rowStep = (size_t)32 * K;

#define STAGE(buf, kt_)                                                        \
  do {                                                                         \
    _Pragma("unroll") for (int p = 0; p < 4; ++p) {                            \
      GLOAD16(aBase + (kt_) + p * rowStep, (u16*)As[buf] + p * 2048 + t * 8);  \
      GLOAD16(bBase + (kt_) + p * rowStep, (u16*)Bs[buf] + p * 2048 + t * 8);  \
    }                                                                          \
  } while (0)

  f32x4 acc[4][4] = {};
  const int nk = K >> 6;
  STAGE(0, 0);
  __syncthreads();
  int cur = 0;
  for (int kt = 0; kt < nk; ++kt) {
    if (kt + 1 < nk) STAGE(cur ^ 1, (kt + 1) << 6);  // loads fly under compute
    bf16x8 af[2][4], bfr[2][4];
#pragma unroll
    for (int kk = 0; kk < 2; ++kk) {
#pragma unroll
      for (int i = 0; i < 4; ++i) {
        const int row_ = wr * 64 + i * 16 + lm;
        af[kk][i] = *(const bf16x8*)(As[cur] + row_ * 64 +
                                     ((((kk << 2) | lg) ^ (row_ & 7)) << 3));
      }
#pragma unroll
      for (int j = 0; j < 4; ++j) {
        const int row_ = wc * 64 + j * 16 + lm;
        bfr[kk][j] = *(const bf16x8*)(Bs[cur] + row_ * 64 +
                                      ((((kk << 2) | lg) ^ (row_ & 7)) << 3));
      }
    }
#pragma unroll
    for (int kk = 0; kk < 2; ++kk)
#pragma unroll
      for (int i = 0; i < 4; ++i)
#pragma unroll
        for (int j = 0; j < 4; ++j)
          acc[i][j] = __builtin_amdgcn_mfma_f32_16x16x32_bf16(af[kk][i], bfr[kk][j],
                                                              acc[i][j], 0, 0, 0);
    __syncthreads();  // drains vmcnt(0): next buffer staged, cur reusable
    cur ^= 1;
  }
#undef STAGE

  const int row0 = bm * 128 + wr * 64 + lg * 4;
  const int col0 = bn * 128 + wc * 64 + lm;
  if (c_bf16) {
    u16* C = (u16*)Cout;
#pragma unroll
    for (int i = 0; i < 4; ++i)
#pragma unroll
      for (int r = 0; r < 4; ++r) {
        u16* crow = C + (size_t)(row0 + i * 16 + r) * N + col0;
#pragma unroll
        for (int j = 0; j < 4; ++j) crow[j * 16] = f2bf(acc[i][j][r]);
      }
  } else {
    float* C = (float*)Cout;
#pragma unroll
    for (int i = 0; i < 4; ++i)
#pragma unroll
      for (int r = 0; r < 4; ++r) {
        float* crow = C + (size_t)(row0 + i * 16 + r) * N + col0;
#pragma unroll
        for (int j = 0; j < 4; ++j) crow[j * 16] = acc[i][j][r];
      }
  }
}

// ------- assemble qf (pre-scaled) ----------
__global__ void k_mk_qf(const u16* __restrict__ qfull, const float* __restrict__ cosb,
                        const float* __restrict__ sinb, u16* __restrict__ qf) {
  const int s = blockIdx.x, h = blockIdx.y, t = threadIdx.x;
  const u16* src = qfull + (size_t)s * (NH * DQK) + h * DQK;
  u16* dst = qf + ((size_t)h * SEQ + s) * DQK;
  dst[t] = f2bf(bf2f(src[t]) * SCALE);
  if (t < 32) {
    float a = bf2f(src[DN + 2 * t]);
    float b = bf2f(src[DN + 2 * t + 1]);
    float c = cosb[(size_t)s * DR + t];
    float sn = sinb[(size_t)s * DR + t];
    dst[DN + t] = f2bf((a * c - b * sn) * SCALE);
    dst[DN + 32 + t] = f2bf((b * c + a * sn) * SCALE);
  }
}

// -------- assemble kf and v_t[h][d][s] --------
__global__ void k_mk_kf_v(const u16* __restrict__ kvfull, const float* __restrict__ krot,
                          int krot_stride, const float* __restrict__ cosb,
                          const float* __restrict__ sinb, u16* __restrict__ kf,
                          u16* __restrict__ vt) {
  const int s = blockIdx.x, h = blockIdx.y, t = threadIdx.x;
  const u16* src = kvfull + (size_t)s * (NH * 256) + h * 256;
  u16* kdst = kf + ((size_t)h * SEQ + s) * DQK;
  kdst[t] = src[t];
  vt[((size_t)h * DV + t) * SEQ + s] = src[DN + t];
  if (t < 32) {
    float a = krot[(size_t)s * krot_stride + 2 * t];
    float b = krot[(size_t)s * krot_stride + 2 * t + 1];
    float c = cosb[(size_t)s * DR + t];
    float sn = sinb[(size_t)s * DR + t];
    kdst[DN + t] = f2bf(a * c - b * sn);
    kdst[DN + 32 + t] = f2bf(b * c + a * sn);
  }
}

// ---------------- flash attention v5: cooperative LDS-staged blocks ----------
__global__ __launch_bounds__(256) void k_attn(
    const u16* __restrict__ qf, const u16* __restrict__ kf, const u16* __restrict__ vt,
    u16* __restrict__ attn_out) {
  __shared__ __align__(16) u16 Ks[2][32 * 192];   // [kv][k-dim], swizzled
  __shared__ __align__(16) u16 Vs[2][128 * 32];   // [d][kv], swizzled
  __shared__ __align__(16) u16 p_lds[4][16][32];

  const int t = threadIdx.x, lane = t & 63, w = t >> 6;
  const int lm = lane & 15, lg = lane >> 4;
  const int bid = blockIdx.x;
  const int x = bid & 7, r0 = bid >> 3;  // r0 in [0,64)
  const int h = x * 2 + (r0 & 1);        // 2 heads per XCD
  const int u = r0 >> 1;                 // [0,32)
  const int seg = u & 1;
  const int tj = 15 - (u >> 1);          // [0,16) longest first
  const int tile_row0 = seg * 1024 + tj * 64;
  const int k_begin = seg * 1024;
  const int n_kt = tj * 2 + 2;

  const int lo_row = tile_row0 + w * 16;
  bf16x8 qfr[6];
  {
    const u16* qp = qf + ((size_t)h * SEQ + (lo_row + lm)) * DQK + lg * 8;
#pragma unroll
    for (int c = 0; c < 6; ++c) qfr[c] = *(const bf16x8*)(qp + c * 32);
  }
  int qrow[4];
#pragma unroll
  for (int r = 0; r < 4; ++r) qrow[r] = lo_row + lg * 4 + r;

  float m_r[4], l_loc[4];
#pragma unroll
  for (int r = 0; r < 4; ++r) { m_r[r] = -3.0e4f; l_loc[r] = 0.f; }
  f32x4 oacc[8] = {};

#define STAGE(buf, kt_)                                                        \
  do {                                                                         \
    const int k0_ = k_begin + (kt_) * 32;                                      \
    _Pragma("unroll") for (int p = 0; p < 3; ++p) {                            \
      const int id = p * 256 + t;                                              \
      const int row = id / 24, colL = id - row * 24;                           \
      const u16* g = kf + ((size_t)h * SEQ + k0_ + row) * DQK +                \
                     ((colL ^ (row & 7)) * 8);                                 \
      GLOAD16(g, (u16*)Ks[buf] + id * 8);                                      \
    }                                                                          \
    _Pragma("unroll") for (int p = 0; p < 2; ++p) {                            \
      const int id = p * 256 + t;                                              \
      const int row = id >> 2, colL = id & 3;                                  \
      const u16* g = vt + ((size_t)h * DV + row) * SEQ + k0_ +                 \
                     ((colL ^ (row & 3)) * 8);                                 \
      GLOAD16(g, (u16*)Vs[buf] + id * 8);                                      \
    }                                                                          \
  } while (0)

#define COMPUTE(buf, kt_)                                                      \
  do {                                                                         \
    const int k0_ = k_begin + (kt_) * 32;                                      \
    f32x4 sc[2] = {};                                                          \
    _Pragma("unroll") for (int n0_ = 0; n0_ < 2; ++n0_)                        \
        _Pragma("unroll") for (int c_ = 0; c_ < 6; ++c_) {                     \
      const int row_ = n0_ * 16 + lm, cc_ = c_ * 4 + lg;                       \
      bf16x8 kfr = *(const bf16x8*)(Ks[buf] + row_ * 192 +                     \
                                    ((cc_ ^ (row_ & 7)) * 8));                 \
      sc[n0_] = __builtin_amdgcn_mfma_f32_16x16x32_bf16(qfr[c_], kfr,          \
                                                        sc[n0_], 0, 0, 0);     \
    }                                                                          \
    float s0a[4], s1a[4];                                                      \
    float over = -1e30f;                                                       \
    {                                                                          \
      const int kc0 = k0_ + lm, kc1 = k0_ + 16 + lm;                           \
      _Pragma("unroll") for (int r = 0; r < 4; ++r) {                          \
        s0a[r] = (kc0 <= qrow[r]) ? sc[0][r] : -1e30f;                         \
        s1a[r] = (kc1 <= qrow[r]) ? sc[1][r] : -1e30f;                         \
        over = fmaxf(over, fmaxf(s0a[r], s1a[r]) - m_r[r]);                    \
      }                                                                        \
    }                                                                          \
    if (__any(over > 8.0f)) {                                                  \
      _Pragma("unroll") for (int r = 0; r < 4; ++r) {                          \
        float mx = fmaxf(s0a[r], s1a[r]);                                      \
        _Pragma("unroll") for (int md = 1; md < 16; md <<= 1)                  \
            mx = fmaxf(mx, __shfl_xor(mx, md, 64));                            \
        float mnew = fmaxf(m_r[r], mx);                                        \
        float alpha = __expf(m_r[r] - mnew);                                   \
        m_r[r] = mnew;                                                         \
        l_loc[r] *= alpha;                                                     \
        _Pragma("unroll") for (int nd = 0; nd < 8; ++nd) oacc[nd][r] *= alpha; \
      }                                                                        \
    }                                                                          \
    _Pragma("unroll") for (int r = 0; r < 4; ++r) {                            \
      float p0 = __expf(s0a[r] - m_r[r]);                                      \
      float p1 = __expf(s1a[r] - m_r[r]);                                      \
      l_loc[r] += p0 + p1;                                                     \
      p_lds[w][lg * 4 + r][lm] = f2bf(p0);                                     \
      p_lds[w][lg * 4 + r][16 + lm] = f2bf(p1);                                \
    }                                                                          \
    asm volatile("s_waitcnt lgkmcnt(0)" ::: "memory");                         \
    __builtin_amdgcn_sched_barrier(0);                                         \
    bf16x8 pa = *(const bf16x8*)(&p_lds[w][lm][lg * 8]);                       \
    _Pragma("unroll") for (int nd = 0; nd < 8; ++nd) {                         \
      const int row_ = nd * 16 + lm;                                           \
      bf16x8 vvf = *(const bf16x8*)(Vs[buf] + row_ * 32 +                      \
                                    ((lg ^ (row_ & 3)) * 8));                  \
      oacc[nd] =                                                               \
          __builtin_amdgcn_mfma_f32_16x16x32_bf16(pa, vvf, oacc[nd], 0, 0, 0); \
    }                                                                          \
  } while (0)

  int cur = 0;
  STAGE(0, 0);
  __syncthreads();
  for (int kt = 0;;) {
    if (kt + 1 < n_kt) STAGE(cur ^ 1, kt + 1);  // loads fly under compute
    COMPUTE(cur, kt);
    ++kt;
    if (kt >= n_kt) break;
    __syncthreads();  // next buffer staged + everyone done with cur
    cur ^= 1;
  }
#undef STAGE
#undef COMPUTE

#pragma unroll
  for (int r = 0; r < 4; ++r) {
    float lt = l_loc[r];
#pragma unroll
    for (int md = 1; md < 16; md <<= 1) lt += __shfl_xor(lt, md, 64);
    float inv = 1.0f / lt;
#pragma unroll
    for (int nd = 0; nd < 8; ++nd)
      attn_out[(size_t)qrow[r] * (NH * DV) + h * DV + nd * 16 + lm] =
          f2bf(oacc[nd][r] * inv);
  }
}

extern "C" void kernel_launch(void* const* d_in, const int* in_sizes, int n_in,
                              void* d_out, int out_size, void* d_ws, size_t ws_size,
                              hipStream_t stream) {
  const float* hs = (const float*)d_in[0];
  const float* cosb = (const float*)d_in[1];
  const float* sinb = (const float*)d_in[2];
  const float* wq_a = (const float*)d_in[3];
  const float* q_a_ln_w = (const float*)d_in[4];
  const float* wq_b = (const float*)d_in[5];
  const float* wkv_a = (const float*)d_in[6];
  const float* kv_a_ln_w = (const float*)d_in[7];
  const float* wkv_b = (const float*)d_in[8];
  const float* wo = (const float*)d_in[9];

  char* ws = (char*)d_ws;
  size_t off = 0;
  auto take = [&](size_t bytes) {
    size_t o = off;
    off += (bytes + 255) & ~(size_t)255;
    return o;
  };
  u16* hs_bf = (u16*)(ws + take((size_t)SEQ * HID * 2));
  u16* wqkva = (u16*)(ws + take((size_t)NKVA * HID * 2));
  u16* wqb = (u16*)(ws + take((size_t)(NH * DQK) * QLR * 2));
  u16* wkvb = (u16*)(ws + take((size_t)(NH * 256) * KVLR * 2));
  u16* wo_bf = (u16*)(ws + take((size_t)HID * (NH * DV) * 2));
  float* qkva = (float*)(ws + take((size_t)SEQ * NKVA * 4));
  u16* q_ln = (u16*)(ws + take((size_t)SEQ * QLR * 2));
  u16* kv_ln = (u16*)(ws + take((size_t)SEQ * KVLR * 2));
  u16* qfull = (u16*)(ws + take((size_t)SEQ * NH * DQK * 2));
  u16* kvfull = (u16*)(ws + take((size_t)SEQ * NH * 256 * 2));
  u16* qf = (u16*)(ws + take((size_t)NH * SEQ * DQK * 2));
  u16* kf = (u16*)(ws + take((size_t)NH * SEQ * DQK * 2));
  u16* vt = (u16*)(ws + take((size_t)NH * DV * SEQ * 2));
  u16* attn = (u16*)(ws + take((size_t)SEQ * NH * DV * 2));
  if (off > ws_size) return;

  auto blocks4 = [](long n) {
    long b = (n / 4 + 255) / 256;
    return (int)(b > 4096 ? 4096 : b);
  };

  k_convert<<<blocks4((long)SEQ * HID), 256, 0, stream>>>(hs, hs_bf, (long)SEQ * HID, (long)SEQ * HID);
  k_convert<<<blocks4((long)QLR * HID), 256, 0, stream>>>(wq_a, wqkva, (long)QLR * HID, (long)QLR * HID);
  k_convert<<<blocks4((long)640 * HID), 256, 0, stream>>>(wkv_a, wqkva + (size_t)QLR * HID,
                                                          (long)(KVLR + DR) * HID, (long)640 * HID);
  k_convert<<<blocks4((long)NH * DQK * QLR), 256, 0, stream>>>(wq_b, wqb, (long)NH * DQK * QLR,
                                                               (long)NH * DQK * QLR);
  k_convert<<<blocks4((long)NH * 256 * KVLR), 256, 0, stream>>>(wkv_b, wkvb, (long)NH * 256 * KVLR,
                                                                (long)NH * 256 * KVLR);
  k_convert<<<blocks4((long)HID * NH * DV), 256, 0, stream>>>(wo, wo_bf, (long)HID * NH * DV,
                                                              (long)HID * NH * DV);

  dim3 g1(NKVA / 128, SEQ / 128);
  k_gemm_nt<<<g1, 256, 0, stream>>>(hs_bf, wqkva, qkva, SEQ, NKVA, HID, 0);

  k_rmsnorm<<<SEQ, 256, 0, stream>>>(qkva, q_a_ln_w, q_ln, NKVA, QLR, 1.0f / QLR);
  k_rmsnorm<<<SEQ, 256, 0, stream>>>(qkva + QLR, kv_a_ln_w, kv_ln, NKVA, KVLR, 1.0f / KVLR);

  dim3 g2(NH * DQK / 128, SEQ / 128);
  k_gemm_nt<<<g2, 256, 0, stream>>>(q_ln, wqb, qfull, SEQ, NH * DQK, QLR, 1);
  dim3 g3(NH * 256 / 128, SEQ / 128);
  k_gemm_nt<<<g3, 256, 0, stream>>>(kv_ln, wkvb, kvfull, SEQ, NH * 256, KVLR, 1);

  k_mk_qf<<<dim3(SEQ, NH), 128, 0, stream>>>(qfull, cosb, sinb, qf);
  k_mk_kf_v<<<dim3(SEQ, NH), 128, 0, stream>>>(kvfull, qkva + (QLR + KVLR), NKVA, cosb, sinb, kf, vt);

  k_attn<<<512, 256, 0, stream>>>(qf, kf, vt, attn);

  dim3 g4(HID / 128, SEQ / 128);
  k_gemm_nt<<<g4, 256, 0, stream>>>(attn, wo_bf, d_out, SEQ, HID, NH * DV, 0);
}

// Round 7
// 221.581 us; speedup vs baseline: 1.6007x; 1.0732x over previous
//
#include <hip/hip_runtime.h>

typedef unsigned short u16;
typedef __attribute__((ext_vector_type(8))) short bf16x8;
typedef __attribute__((ext_vector_type(4))) float f32x4;

#define HID 2048
#define NH 16
#define QLR 1536
#define KVLR 512
#define DR 64
#define DN 128
#define DQK 192
#define DV 128
#define SEQ 2048
#define NKVA 2176
#define SCALE 0.07216878364870323f  // 192^-0.5

static __device__ __forceinline__ u16 f2bf(float f) {
  unsigned v = __builtin_bit_cast(unsigned, f);
  v = v + 0x7fffu + ((v >> 16) & 1u);
  return (u16)(v >> 16);
}
static __device__ __forceinline__ float bf2f(u16 u) {
  unsigned v = ((unsigned)u) << 16;
  return __builtin_bit_cast(float, v);
}

#define GLOAD16(gp, lp)                                                        \
  __builtin_amdgcn_global_load_lds(                                            \
      (const __attribute__((address_space(1))) void*)(gp),                     \
      (__attribute__((address_space(3))) void*)(lp), 16, 0, 0)

// ---------------- f32 -> bf16 convert; trailing region (i >= nsrc) zeroed ----
__global__ void k_convert(const float* __restrict__ src, u16* __restrict__ dst,
                          long nsrc, long ndst) {
  long i = ((long)blockIdx.x * blockDim.x + threadIdx.x) * 4;
  long stride = (long)gridDim.x * blockDim.x * 4;
  for (; i < ndst; i += stride) {
    u16 o0 = 0, o1 = 0, o2 = 0, o3 = 0;
    if (i < nsrc) {
      const float4 f = *(const float4*)(src + i);
      o0 = f2bf(f.x); o1 = f2bf(f.y); o2 = f2bf(f.z); o3 = f2bf(f.w);
    }
    u16* d = dst + i;
    d[0] = o0; d[1] = o1; d[2] = o2; d[3] = o3;
  }
}

// ---------------- row RMSNorm ----------------
__global__ void k_rmsnorm(const float* __restrict__ X, const float* __restrict__ w,
                          u16* __restrict__ Y, int xstride, int cols, float inv_cols) {
  const int row = blockIdx.x;
  const int t = threadIdx.x;
  const float* x = X + (size_t)row * xstride;
  float ss = 0.f;
  for (int i = t * 4; i < cols; i += 1024) {
    float4 v = *(const float4*)(x + i);
    ss += v.x * v.x + v.y * v.y + v.z * v.z + v.w * v.w;
  }
#pragma unroll
  for (int m = 1; m < 64; m <<= 1) ss += __shfl_xor(ss, m, 64);
  __shared__ float red[4];
  if ((t & 63) == 0) red[t >> 6] = ss;
  __syncthreads();
  float tot = red[0] + red[1] + red[2] + red[3];
  float r = rsqrtf(tot * inv_cols + 1e-6f);
  for (int i = t * 4; i < cols; i += 1024) {
    float4 v = *(const float4*)(x + i);
    float4 g = *(const float4*)(w + i);
    u16* y = Y + (size_t)row * cols + i;
    y[0] = f2bf(v.x * r * g.x);
    y[1] = f2bf(v.y * r * g.y);
    y[2] = f2bf(v.z * r * g.z);
    y[3] = f2bf(v.w * r * g.w);
  }
}

// ---------------- NT GEMM v3: 128x128, BK=64, counted-vmcnt 2-phase ---------
// Per K-step: vmcnt(8) [older stage only] -> barrier -> ds_read -> lgkm(0)
// -> barrier -> STAGE(kt+2) -> MFMA@prio1. Loads never drain to 0 mid-loop.
__global__ __launch_bounds__(256) void k_gemm_nt(
    const u16* __restrict__ A, const u16* __restrict__ B, void* __restrict__ Cout,
    int M, int N, int K, int c_bf16) {
  __shared__ __align__(16) u16 As[2][8192];   // [buf][128 rows x 64 cols]
  __shared__ __align__(16) u16 Bs[2][8192];
  const int t = threadIdx.x;
  const int lane = t & 63;
  const int w = t >> 6, wr = w >> 1, wc = w & 1;
  const int lm = lane & 15, lg = lane >> 4;

  const int nwg = gridDim.x * gridDim.y;
  int bid = blockIdx.y * gridDim.x + blockIdx.x;
  if ((nwg & 7) == 0) bid = (bid & 7) * (nwg >> 3) + (bid >> 3);
  const int bm = bid % gridDim.y;
  const int bn = bid / gridDim.y;

  const int srow = t >> 3;
  const int scol = ((t & 7) ^ (srow & 7)) * 8;
  const u16* aBase = A + (size_t)(bm * 128 + srow) * K + scol;
  const u16* bBase = B + (size_t)(bn * 128 + srow) * K + scol;
  const size_t rowStep = (size_t)32 * K;

#define STAGE(buf, kt_)                                                        \
  do {                                                                         \
    _Pragma("unroll") for (int p = 0; p < 4; ++p) {                            \
      GLOAD16(aBase + (kt_) + p * rowStep, (u16*)As[buf] + p * 2048 + t * 8);  \
      GLOAD16(bBase + (kt_) + p * rowStep, (u16*)Bs[buf] + p * 2048 + t * 8);  \
    }                                                                          \
  } while (0)

  f32x4 acc[4][4] = {};
  const int nk = K >> 6;
  STAGE(0, 0);
  if (nk > 1) STAGE(1, 64);
  int cur = 0;
  for (int kt = 0; kt < nk; ++kt) {
    if (kt + 1 < nk) asm volatile("s_waitcnt vmcnt(8)" ::: "memory");
    else             asm volatile("s_waitcnt vmcnt(0)" ::: "memory");
    __builtin_amdgcn_s_barrier();
    __builtin_amdgcn_sched_barrier(0);
    bf16x8 af[2][4], bfr[2][4];
#pragma unroll
    for (int kk = 0; kk < 2; ++kk) {
#pragma unroll
      for (int i = 0; i < 4; ++i) {
        const int row_ = wr * 64 + i * 16 + lm;
        af[kk][i] = *(const bf16x8*)(As[cur] + row_ * 64 +
                                     ((((kk << 2) | lg) ^ (row_ & 7)) << 3));
      }
#pragma unroll
      for (int j = 0; j < 4; ++j) {
        const int row_ = wc * 64 + j * 16 + lm;
        bfr[kk][j] = *(const bf16x8*)(Bs[cur] + row_ * 64 +
                                      ((((kk << 2) | lg) ^ (row_ & 7)) << 3));
      }
    }
    asm volatile("s_waitcnt lgkmcnt(0)" ::: "memory");
    __builtin_amdgcn_sched_barrier(0);
    __builtin_amdgcn_s_barrier();
    __builtin_amdgcn_sched_barrier(0);
    if (kt + 2 < nk) STAGE(cur, (kt + 2) << 6);  // stays in flight past barrier
    __builtin_amdgcn_s_setprio(1);
#pragma unroll
    for (int kk = 0; kk < 2; ++kk)
#pragma unroll
      for (int i = 0; i < 4; ++i)
#pragma unroll
        for (int j = 0; j < 4; ++j)
          acc[i][j] = __builtin_amdgcn_mfma_f32_16x16x32_bf16(af[kk][i], bfr[kk][j],
                                                              acc[i][j], 0, 0, 0);
    __builtin_amdgcn_s_setprio(0);
    cur ^= 1;
  }
#undef STAGE

  const int row0 = bm * 128 + wr * 64 + lg * 4;
  const int col0 = bn * 128 + wc * 64 + lm;
  if (c_bf16) {
    u16* C = (u16*)Cout;
#pragma unroll
    for (int i = 0; i < 4; ++i)
#pragma unroll
      for (int r = 0; r < 4; ++r) {
        u16* crow = C + (size_t)(row0 + i * 16 + r) * N + col0;
#pragma unroll
        for (int j = 0; j < 4; ++j) crow[j * 16] = f2bf(acc[i][j][r]);
      }
  } else {
    float* C = (float*)Cout;
#pragma unroll
    for (int i = 0; i < 4; ++i)
#pragma unroll
      for (int r = 0; r < 4; ++r) {
        float* crow = C + (size_t)(row0 + i * 16 + r) * N + col0;
#pragma unroll
        for (int j = 0; j < 4; ++j) crow[j * 16] = acc[i][j][r];
      }
  }
}

// ------- assemble qf (pre-scaled) ----------
__global__ void k_mk_qf(const u16* __restrict__ qfull, const float* __restrict__ cosb,
                        const float* __restrict__ sinb, u16* __restrict__ qf) {
  const int s = blockIdx.x, h = blockIdx.y, t = threadIdx.x;
  const u16* src = qfull + (size_t)s * (NH * DQK) + h * DQK;
  u16* dst = qf + ((size_t)h * SEQ + s) * DQK;
  dst[t] = f2bf(bf2f(src[t]) * SCALE);
  if (t < 32) {
    float a = bf2f(src[DN + 2 * t]);
    float b = bf2f(src[DN + 2 * t + 1]);
    float c = cosb[(size_t)s * DR + t];
    float sn = sinb[(size_t)s * DR + t];
    dst[DN + t] = f2bf((a * c - b * sn) * SCALE);
    dst[DN + 32 + t] = f2bf((b * c + a * sn) * SCALE);
  }
}

// -------- assemble kf and v_t[h][d][s] --------
__global__ void k_mk_kf_v(const u16* __restrict__ kvfull, const float* __restrict__ krot,
                          int krot_stride, const float* __restrict__ cosb,
                          const float* __restrict__ sinb, u16* __restrict__ kf,
                          u16* __restrict__ vt) {
  const int s = blockIdx.x, h = blockIdx.y, t = threadIdx.x;
  const u16* src = kvfull + (size_t)s * (NH * 256) + h * 256;
  u16* kdst = kf + ((size_t)h * SEQ + s) * DQK;
  kdst[t] = src[t];
  vt[((size_t)h * DV + t) * SEQ + s] = src[DN + t];
  if (t < 32) {
    float a = krot[(size_t)s * krot_stride + 2 * t];
    float b = krot[(size_t)s * krot_stride + 2 * t + 1];
    float c = cosb[(size_t)s * DR + t];
    float sn = sinb[(size_t)s * DR + t];
    kdst[DN + t] = f2bf(a * c - b * sn);
    kdst[DN + 32 + t] = f2bf(b * c + a * sn);
  }
}

// ---------------- flash attention v6: counted-vmcnt + unmasked fast path ----
__global__ __launch_bounds__(256) void k_attn(
    const u16* __restrict__ qf, const u16* __restrict__ kf, const u16* __restrict__ vt,
    u16* __restrict__ attn_out) {
  __shared__ __align__(16) u16 Ks[2][32 * 192];   // [kv][k-dim], swizzled
  __shared__ __align__(16) u16 Vs[2][128 * 32];   // [d][kv], swizzled
  __shared__ __align__(16) u16 p_lds[4][16][32];

  const int t = threadIdx.x, lane = t & 63, w = t >> 6;
  const int lm = lane & 15, lg = lane >> 4;
  const int bid = blockIdx.x;
  const int x = bid & 7, r0 = bid >> 3;  // r0 in [0,64)
  const int h = x * 2 + (r0 & 1);        // 2 heads per XCD
  const int u = r0 >> 1;                 // [0,32)
  const int seg = u & 1;
  const int tj = 15 - (u >> 1);          // [0,16) longest first
  const int tile_row0 = seg * 1024 + tj * 64;
  const int k_begin = seg * 1024;
  const int n_kt = tj * 2 + 2;

  const int lo_row = tile_row0 + w * 16;
  bf16x8 qfr[6];
  {
    const u16* qp = qf + ((size_t)h * SEQ + (lo_row + lm)) * DQK + lg * 8;
#pragma unroll
    for (int c = 0; c < 6; ++c) qfr[c] = *(const bf16x8*)(qp + c * 32);
  }
  int qrow[4];
#pragma unroll
  for (int r = 0; r < 4; ++r) qrow[r] = lo_row + lg * 4 + r;

  float m_r[4], l_loc[4];
#pragma unroll
  for (int r = 0; r < 4; ++r) { m_r[r] = -3.0e4f; l_loc[r] = 0.f; }
  f32x4 oacc[8] = {};

#define STAGE(buf, kt_)                                                        \
  do {                                                                         \
    const int k0_ = k_begin + (kt_) * 32;                                      \
    _Pragma("unroll") for (int p = 0; p < 3; ++p) {                            \
      const int id = p * 256 + t;                                              \
      const int row = id / 24, colL = id - row * 24;                           \
      const u16* g = kf + ((size_t)h * SEQ + k0_ + row) * DQK +                \
                     ((colL ^ (row & 7)) * 8);                                 \
      GLOAD16(g, (u16*)Ks[buf] + id * 8);                                      \
    }                                                                          \
    _Pragma("unroll") for (int p = 0; p < 2; ++p) {                            \
      const int id = p * 256 + t;                                              \
      const int row = id >> 2, colL = id & 3;                                  \
      const u16* g = vt + ((size_t)h * DV + row) * SEQ + k0_ +                 \
                     ((colL ^ (row & 3)) * 8);                                 \
      GLOAD16(g, (u16*)Vs[buf] + id * 8);                                      \
    }                                                                          \
  } while (0)

#define COMPUTE(buf, kt_)                                                      \
  do {                                                                         \
    const int k0_ = k_begin + (kt_) * 32;                                      \
    f32x4 sc[2] = {};                                                          \
    __builtin_amdgcn_s_setprio(1);                                             \
    _Pragma("unroll") for (int n0_ = 0; n0_ < 2; ++n0_)                        \
        _Pragma("unroll") for (int c_ = 0; c_ < 6; ++c_) {                     \
      const int row_ = n0_ * 16 + lm, cc_ = c_ * 4 + lg;                       \
      bf16x8 kfr = *(const bf16x8*)(Ks[buf] + row_ * 192 +                     \
                                    ((cc_ ^ (row_ & 7)) * 8));                 \
      sc[n0_] = __builtin_amdgcn_mfma_f32_16x16x32_bf16(qfr[c_], kfr,          \
                                                        sc[n0_], 0, 0, 0);     \
    }                                                                          \
    __builtin_amdgcn_s_setprio(0);                                             \
    float s0a[4], s1a[4];                                                      \
    float over = -1e30f;                                                       \
    if (lo_row >= k0_ + 31) { /* strictly below diagonal: no mask needed */    \
      _Pragma("unroll") for (int r = 0; r < 4; ++r) {                          \
        s0a[r] = sc[0][r];                                                     \
        s1a[r] = sc[1][r];                                                     \
        over = fmaxf(over, fmaxf(s0a[r], s1a[r]) - m_r[r]);                    \
      }                                                                        \
    } else {                                                                   \
      const int kc0 = k0_ + lm, kc1 = k0_ + 16 + lm;                           \
      _Pragma("unroll") for (int r = 0; r < 4; ++r) {                          \
        s0a[r] = (kc0 <= qrow[r]) ? sc[0][r] : -1e30f;                         \
        s1a[r] = (kc1 <= qrow[r]) ? sc[1][r] : -1e30f;                         \
        over = fmaxf(over, fmaxf(s0a[r], s1a[r]) - m_r[r]);                    \
      }                                                                        \
    }                                                                          \
    if (__any(over > 8.0f)) {                                                  \
      _Pragma("unroll") for (int r = 0; r < 4; ++r) {                          \
        float mx = fmaxf(s0a[r], s1a[r]);                                      \
        _Pragma("unroll") for (int md = 1; md < 16; md <<= 1)                  \
            mx = fmaxf(mx, __shfl_xor(mx, md, 64));                            \
        float mnew = fmaxf(m_r[r], mx);                                        \
        float alpha = __expf(m_r[r] - mnew);                                   \
        m_r[r] = mnew;                                                         \
        l_loc[r] *= alpha;                                                     \
        _Pragma("unroll") for (int nd = 0; nd < 8; ++nd) oacc[nd][r] *= alpha; \
      }                                                                        \
    }                                                                          \
    _Pragma("unroll") for (int r = 0; r < 4; ++r) {                            \
      float p0 = __expf(s0a[r] - m_r[r]);                                      \
      float p1 = __expf(s1a[r] - m_r[r]);                                      \
      l_loc[r] += p0 + p1;                                                     \
      p_lds[w][lg * 4 + r][lm] = f2bf(p0);                                     \
      p_lds[w][lg * 4 + r][16 + lm] = f2bf(p1);                                \
    }                                                                          \
    asm volatile("s_waitcnt lgkmcnt(0)" ::: "memory");                         \
    __builtin_amdgcn_sched_barrier(0);                                         \
    bf16x8 pa = *(const bf16x8*)(&p_lds[w][lm][lg * 8]);                       \
    __builtin_amdgcn_s_setprio(1);                                             \
    _Pragma("unroll") for (int nd = 0; nd < 8; ++nd) {                         \
      const int row_ = nd * 16 + lm;                                           \
      bf16x8 vvf = *(const bf16x8*)(Vs[buf] + row_ * 32 +                      \
                                    ((lg ^ (row_ & 3)) * 8));                  \
      oacc[nd] =                                                               \
          __builtin_amdgcn_mfma_f32_16x16x32_bf16(pa, vvf, oacc[nd], 0, 0, 0); \
    }                                                                          \
    __builtin_amdgcn_s_setprio(0);                                             \
  } while (0)

  int cur = 0;
  STAGE(0, 0);
  STAGE(1, 1);  // n_kt >= 2 always
  for (int kt = 0; kt < n_kt; ++kt) {
    if (kt + 1 < n_kt) asm volatile("s_waitcnt vmcnt(5)" ::: "memory");
    else               asm volatile("s_waitcnt vmcnt(0)" ::: "memory");
    __builtin_amdgcn_s_barrier();
    __builtin_amdgcn_sched_barrier(0);
    COMPUTE(cur, kt);
    asm volatile("s_waitcnt lgkmcnt(0)" ::: "memory");
    __builtin_amdgcn_sched_barrier(0);
    __builtin_amdgcn_s_barrier();
    __builtin_amdgcn_sched_barrier(0);
    if (kt + 2 < n_kt) STAGE(cur, kt + 2);  // stays in flight past barrier
    cur ^= 1;
  }
#undef STAGE
#undef COMPUTE

#pragma unroll
  for (int r = 0; r < 4; ++r) {
    float lt = l_loc[r];
#pragma unroll
    for (int md = 1; md < 16; md <<= 1) lt += __shfl_xor(lt, md, 64);
    float inv = 1.0f / lt;
#pragma unroll
    for (int nd = 0; nd < 8; ++nd)
      attn_out[(size_t)qrow[r] * (NH * DV) + h * DV + nd * 16 + lm] =
          f2bf(oacc[nd][r] * inv);
  }
}

extern "C" void kernel_launch(void* const* d_in, const int* in_sizes, int n_in,
                              void* d_out, int out_size, void* d_ws, size_t ws_size,
                              hipStream_t stream) {
  const float* hs = (const float*)d_in[0];
  const float* cosb = (const float*)d_in[1];
  const float* sinb = (const float*)d_in[2];
  const float* wq_a = (const float*)d_in[3];
  const float* q_a_ln_w = (const float*)d_in[4];
  const float* wq_b = (const float*)d_in[5];
  const float* wkv_a = (const float*)d_in[6];
  const float* kv_a_ln_w = (const float*)d_in[7];
  const float* wkv_b = (const float*)d_in[8];
  const float* wo = (const float*)d_in[9];

  char* ws = (char*)d_ws;
  size_t off = 0;
  auto take = [&](size_t bytes) {
    size_t o = off;
    off += (bytes + 255) & ~(size_t)255;
    return o;
  };
  u16* hs_bf = (u16*)(ws + take((size_t)SEQ * HID * 2));
  u16* wqkva = (u16*)(ws + take((size_t)NKVA * HID * 2));
  u16* wqb = (u16*)(ws + take((size_t)(NH * DQK) * QLR * 2));
  u16* wkvb = (u16*)(ws + take((size_t)(NH * 256) * KVLR * 2));
  u16* wo_bf = (u16*)(ws + take((size_t)HID * (NH * DV) * 2));
  float* qkva = (float*)(ws + take((size_t)SEQ * NKVA * 4));
  u16* q_ln = (u16*)(ws + take((size_t)SEQ * QLR * 2));
  u16* kv_ln = (u16*)(ws + take((size_t)SEQ * KVLR * 2));
  u16* qfull = (u16*)(ws + take((size_t)SEQ * NH * DQK * 2));
  u16* kvfull = (u16*)(ws + take((size_t)SEQ * NH * 256 * 2));
  u16* qf = (u16*)(ws + take((size_t)NH * SEQ * DQK * 2));
  u16* kf = (u16*)(ws + take((size_t)NH * SEQ * DQK * 2));
  u16* vt = (u16*)(ws + take((size_t)NH * DV * SEQ * 2));
  u16* attn = (u16*)(ws + take((size_t)SEQ * NH * DV * 2));
  if (off > ws_size) return;

  auto blocks4 = [](long n) {
    long b = (n / 4 + 255) / 256;
    return (int)(b > 4096 ? 4096 : b);
  };

  k_convert<<<blocks4((long)SEQ * HID), 256, 0, stream>>>(hs, hs_bf, (long)SEQ * HID, (long)SEQ * HID);
  k_convert<<<blocks4((long)QLR * HID), 256, 0, stream>>>(wq_a, wqkva, (long)QLR * HID, (long)QLR * HID);
  k_convert<<<blocks4((long)640 * HID), 256, 0, stream>>>(wkv_a, wqkva + (size_t)QLR * HID,
                                                          (long)(KVLR + DR) * HID, (long)640 * HID);
  k_convert<<<blocks4((long)NH * DQK * QLR), 256, 0, stream>>>(wq_b, wqb, (long)NH * DQK * QLR,
                                                               (long)NH * DQK * QLR);
  k_convert<<<blocks4((long)NH * 256 * KVLR), 256, 0, stream>>>(wkv_b, wkvb, (long)NH * 256 * KVLR,
                                                                (long)NH * 256 * KVLR);
  k_convert<<<blocks4((long)HID * NH * DV), 256, 0, stream>>>(wo, wo_bf, (long)HID * NH * DV,
                                                              (long)HID * NH * DV);

  dim3 g1(NKVA / 128, SEQ / 128);
  k_gemm_nt<<<g1, 256, 0, stream>>>(hs_bf, wqkva, qkva, SEQ, NKVA, HID, 0);

  k_rmsnorm<<<SEQ, 256, 0, stream>>>(qkva, q_a_ln_w, q_ln, NKVA, QLR, 1.0f / QLR);
  k_rmsnorm<<<SEQ, 256, 0, stream>>>(qkva + QLR, kv_a_ln_w, kv_ln, NKVA, KVLR, 1.0f / KVLR);

  dim3 g2(NH * DQK / 128, SEQ / 128);
  k_gemm_nt<<<g2, 256, 0, stream>>>(q_ln, wqb, qfull, SEQ, NH * DQK, QLR, 1);
  dim3 g3(NH * 256 / 128, SEQ / 128);
  k_gemm_nt<<<g3, 256, 0, stream>>>(kv_ln, wkvb, kvfull, SEQ, NH * 256, KVLR, 1);

  k_mk_qf<<<dim3(SEQ, NH), 128, 0, stream>>>(qfull, cosb, sinb, qf);
  k_mk_kf_v<<<dim3(SEQ, NH), 128, 0, stream>>>(kvfull, qkva + (QLR + KVLR), NKVA, cosb, sinb, kf, vt);

  k_attn<<<512, 256, 0, stream>>>(qf, kf, vt, attn);

  dim3 g4(HID / 128, SEQ / 128);
  k_gemm_nt<<<g4, 256, 0, stream>>>(attn, wo_bf, d_out, SEQ, HID, NH * DV, 0);
}